// Round 6
// baseline (99.831 us; speedup 1.0000x reference)
//
#include <hip/hip_runtime.h>
#include <hip/hip_bf16.h>
#include <math.h>

#define B_ 16
#define L_ 2048
#define H_ 1024
#define A_ 1024
#define C_ 5

#define NSPLIT 4                 // A-dim split across blocks in MFMA part
#define MT 32                    // rows per tile
#define NTB 256                  // a-cols per block (one per as-slice)
#define KPH 256                  // K per staging phase
#define TPB 16                   // tiles per batch (16*32=512 >= max masked 511)
#define KC_BLOCKS (B_ * TPB * NSPLIT)   // 1024 MFMA blocks
#define KE_BLOCKS (B_ * L_ / 8)         // 4096 streaming blocks (8 rows each)
#define KW_BLOCKS (A_ * H_ / (256 * 8)) // 512 W-convert blocks

typedef __attribute__((ext_vector_type(8))) short short8v;
typedef __attribute__((ext_vector_type(4))) float float4v;

// ---- workspace layout (bytes) ----
static constexpr size_t OFF_SCAL   = 0;        // 2 f: denom, wsum
static constexpr size_t OFF_END    = 64;       // B ints
static constexpr size_t OFF_CNT    = 192;      // B ints
static constexpr size_t OFF_STARTS = 320;      // B*C ints
static constexpr size_t OFF_LIST   = 4096;                              // B*L ints
static constexpr size_t OFF_W16    = OFF_LIST + (size_t)B_ * L_ * 4;    // A*H bf16
static constexpr size_t OFF_PP     = OFF_W16 + (size_t)A_ * H_ * 2;     // NSPLIT*B*L f
static constexpr size_t OFF_D      = OFF_PP + (size_t)NSPLIT * B_ * L_ * 4;  // B*L f

static __device__ __forceinline__ unsigned short f2bf(float f) {
  unsigned u = __float_as_uint(f);
  unsigned r = (u >> 16) & 1u;
  return (unsigned short)((u + 0x7fffu + r) >> 16);
}

// ============ kernel 1: kWA — masks + scalars + W f32->bf16 ============
__global__ __launch_bounds__(256) void kWA(const int* __restrict__ attn,
                                           const int* __restrict__ mlm,
                                           const float* __restrict__ query,
                                           const float* __restrict__ Wcls,
                                           const float* __restrict__ Wh,
                                           float* __restrict__ ws_scal,
                                           int* __restrict__ endv,
                                           int* __restrict__ cnt,
                                           int* __restrict__ starts,
                                           int* __restrict__ list,
                                           unsigned short* __restrict__ W16) {
  __shared__ int   wsh[4];
  __shared__ float sf1[256];
  __shared__ float sf2[256];
  const int bid = blockIdx.x;
  const int t = threadIdx.x;

  if (bid < B_) {
    const int b = bid;
    const int* arow = attn + (size_t)b * L_;
    const int* mrow = mlm + (size_t)b * L_;
    const int w = t >> 6;
    const int lane = t & 63;
    const int base = t * 8;

    // ---- pass 1: attn==0 compaction (ascending) ----
    int loc[8];
    int lc = 0;
#pragma unroll
    for (int j = 0; j < 8; ++j) {
      int l = base + j;
      if (arow[l] == 0) loc[lc++] = l;
    }
    int incl = lc;
#pragma unroll
    for (int o = 1; o < 64; o <<= 1) {
      int v = __shfl_up(incl, o, 64);
      if (lane >= o) incl += v;
    }
    if (lane == 63) wsh[w] = incl;
    __syncthreads();
    int pre = 0, total = 0;
#pragma unroll
    for (int i = 0; i < 4; ++i) {
      int s = wsh[i];
      if (i < w) pre += s;
      total += s;
    }
    int excl = pre + incl - lc;
    int* lrow = list + (size_t)b * L_;
    for (int j = 0; j < lc; ++j) lrow[excl + j] = loc[j];
    if (t == 0) {
      cnt[b] = total;
      endv[b] = L_ - total;
    }
    __syncthreads();

    // ---- pass 2: mlm>0 markers ----
    int mloc[8];
    int mc = 0;
#pragma unroll
    for (int j = 0; j < 8; ++j) {
      int l = base + j;
      if (mrow[l] > 0) mloc[mc++] = l;
    }
    int incl2 = mc;
#pragma unroll
    for (int o = 1; o < 64; o <<= 1) {
      int v = __shfl_up(incl2, o, 64);
      if (lane >= o) incl2 += v;
    }
    if (lane == 63) wsh[w] = incl2;
    __syncthreads();
    int pre2 = 0;
#pragma unroll
    for (int i = 0; i < 4; ++i) {
      if (i < w) pre2 += wsh[i];
    }
    int excl2 = pre2 + incl2 - mc;
    for (int j = 0; j < mc; ++j) {
      int idx = excl2 + j;
      if (idx < C_) starts[b * C_ + idx] = mloc[j];
    }
  } else if (bid == B_) {
    // ---- scalars ----
    float s = 0.f, s2 = 0.f;
    for (int i = t; i < A_; i += 256) {
      float q = query[i];
      s += q;
      s2 = fmaf(q, q, s2);
    }
    sf1[t] = s;
    sf2[t] = s2;
    __syncthreads();
    for (int off = 128; off >= 1; off >>= 1) {
      if (t < off) {
        sf1[t] += sf1[t + off];
        sf2[t] += sf2[t + off];
      }
      __syncthreads();
    }
    float qsum = sf1[0], qsq = sf2[0];
    __syncthreads();
    float wv = 0.f;
    for (int i = t; i < H_; i += 256) wv += Wcls[i];
    sf1[t] = wv;
    __syncthreads();
    for (int off = 128; off >= 1; off >>= 1) {
      if (t < off) sf1[t] += sf1[t + off];
      __syncthreads();
    }
    if (t == 0) {
      float var = (qsq - qsum * qsum / (float)A_) / (float)(A_ - 1);
      ws_scal[0] = sqrtf((float)A_ * var);
      ws_scal[1] = sf1[0];
    }
  } else {
    // ---- W conversion ----
    const size_t i = ((size_t)(bid - B_ - 1) * 256 + t) * 8;
    float4 u0 = *(const float4*)(Wh + i);
    float4 u1 = *(const float4*)(Wh + i + 4);
    union { short8v v; unsigned short h[8]; } o;
    o.h[0] = f2bf(u0.x); o.h[1] = f2bf(u0.y); o.h[2] = f2bf(u0.z); o.h[3] = f2bf(u0.w);
    o.h[4] = f2bf(u1.x); o.h[5] = f2bf(u1.y); o.h[6] = f2bf(u1.z); o.h[7] = f2bf(u1.w);
    *(short8v*)(W16 + i) = o.v;
  }
}

// ============ kernel 2: kMain — MFMA probs GEMM + full-row W_cls dots ============
// bids [0, KC_BLOCKS): MFMA; XCD-sibling layout: as = (p>>3)&3, tb = (p&7)|((p>>5)<<3)
//   -> the 4 as-siblings of a tile share p%8 (same XCD) for X L2 reuse.
//   W (bf16) is NOT staged in LDS: B-fragments load straight from L2.
// bids [KC_BLOCKS, +KE_BLOCKS): streaming, 2 rows per wave, d[row]=dot(row,Wcls)
__global__ __launch_bounds__(256) void kMain(const float* __restrict__ inp,
                                             const unsigned short* __restrict__ W16,
                                             const float* __restrict__ bh,
                                             const float* __restrict__ query,
                                             const float* __restrict__ Wcls,
                                             const int* __restrict__ attn,
                                             const int* __restrict__ cnt,
                                             const int* __restrict__ list,
                                             float* __restrict__ probpart,
                                             float* __restrict__ d) {
  __shared__ __align__(16) unsigned short Xs[MT][KPH + 8];  // 32x264 bf16 = 16.9 KB
  __shared__ float red[4][MT];

  const int bid = blockIdx.x;
  const int t = threadIdx.x;
  const int w = t >> 6;
  const int lane = t & 63;

  if (bid >= KC_BLOCKS) {
    // ---- streaming part: 2 rows per wave ----
    const int r0 = (bid - KC_BLOCKS) * 8 + w * 2;
    const int a0v = attn[r0];
    const int a1v = attn[r0 + 1];
    if ((a0v | a1v) == 0) return;
    float4 wv[4];
#pragma unroll
    for (int k = 0; k < 4; ++k) wv[k] = *(const float4*)(Wcls + k * 256 + lane * 4);
    const float* p0 = inp + (size_t)r0 * H_;
    float4 v0[4], v1[4];
    if (a0v) {
#pragma unroll
      for (int k = 0; k < 4; ++k) v0[k] = *(const float4*)(p0 + k * 256 + lane * 4);
    }
    if (a1v) {
#pragma unroll
      for (int k = 0; k < 4; ++k) v1[k] = *(const float4*)(p0 + H_ + k * 256 + lane * 4);
    }
    if (a0v) {
      float acc = 0.f;
#pragma unroll
      for (int k = 0; k < 4; ++k)
        acc += v0[k].x * wv[k].x + v0[k].y * wv[k].y + v0[k].z * wv[k].z + v0[k].w * wv[k].w;
#pragma unroll
      for (int o = 1; o < 64; o <<= 1) acc += __shfl_xor(acc, o, 64);
      if (lane == 0) d[r0] = acc;
    }
    if (a1v) {
      float acc = 0.f;
#pragma unroll
      for (int k = 0; k < 4; ++k)
        acc += v1[k].x * wv[k].x + v1[k].y * wv[k].y + v1[k].z * wv[k].z + v1[k].w * wv[k].w;
#pragma unroll
      for (int o = 1; o < 64; o <<= 1) acc += __shfl_xor(acc, o, 64);
      if (lane == 0) d[r0 + 1] = acc;
    }
    return;
  }

  // ---- MFMA part ----
  const int as = (bid >> 3) & 3;
  const int tb = (bid & 7) | ((bid >> 5) << 3);   // [0, 256)
  const int b = tb >> 4;
  const int tile = tb & 15;
  const int c0 = cnt[b];
  if (tile * MT >= c0) return;

  const int lg = lane >> 4;
  const int lc = lane & 15;
  const int a0 = as * NTB;

  // staging decomposition: row = t>>3, col chunk = (t&7)*32 (32 f32 per thread/phase)
  const int srow = t >> 3;
  const int scol = (t & 7) * 32;
  const int gi = tile * MT + srow;
  const int gidx = (gi < c0) ? gi : (c0 - 1);     // clamp; duplicate rows harmless
  const int xl = list[(size_t)b * L_ + gidx];
  const float* xptr = inp + ((size_t)(b * L_ + xl)) * H_ + scol;

  // per-lane W row pointer: B-fragment rows are a0 + w*64 + n*16 + lc
  const unsigned short* wptr = W16 + (size_t)(a0 + w * 64 + lc) * H_;

  float4v acc[2][4];
#pragma unroll
  for (int m = 0; m < 2; ++m)
#pragma unroll
    for (int n = 0; n < 4; ++n) acc[m][n] = (float4v){0.f, 0.f, 0.f, 0.f};

  for (int ph = 0; ph < H_ / KPH; ++ph) {
    __syncthreads();   // previous phase's LDS reads done
    // stage X chunk: 32 rows x 256 cols (f32 -> bf16)
#pragma unroll
    for (int j = 0; j < 4; ++j) {
      float4 u0 = *(const float4*)(xptr + ph * KPH + j * 8);
      float4 u1 = *(const float4*)(xptr + ph * KPH + j * 8 + 4);
      union { short8v v; unsigned short h[8]; } o;
      o.h[0] = f2bf(u0.x); o.h[1] = f2bf(u0.y); o.h[2] = f2bf(u0.z); o.h[3] = f2bf(u0.w);
      o.h[4] = f2bf(u1.x); o.h[5] = f2bf(u1.y); o.h[6] = f2bf(u1.z); o.h[7] = f2bf(u1.w);
      *(short8v*)&Xs[srow][scol + j * 8] = o.v;
    }
    __syncthreads();   // tile ready
    // 8 barrier-free K=32 sub-steps; W loads pipeline from L2 under MFMA
#pragma unroll
    for (int kk = 0; kk < 8; ++kk) {
      const int off = kk * 32 + lg * 8;
      short8v av0 = *(const short8v*)&Xs[lc][off];
      short8v av1 = *(const short8v*)&Xs[16 + lc][off];
#pragma unroll
      for (int n = 0; n < 4; ++n) {
        short8v bv = *(const short8v*)(wptr + (size_t)n * 16 * H_ + ph * KPH + off);
        acc[0][n] = __builtin_amdgcn_mfma_f32_16x16x32_bf16(av0, bv, acc[0][n], 0, 0, 0);
        acc[1][n] = __builtin_amdgcn_mfma_f32_16x16x32_bf16(av1, bv, acc[1][n], 0, 0, 0);
      }
    }
  }

  // epilogue: bias + tanh + *query, reduce over this wave's 64 a-cols
  float pp[2][4];
#pragma unroll
  for (int m = 0; m < 2; ++m)
#pragma unroll
    for (int r = 0; r < 4; ++r) pp[m][r] = 0.f;

#pragma unroll
  for (int n = 0; n < 4; ++n) {
    const int ag = a0 + w * 64 + n * 16 + lc;
    const float q = query[ag];
    const float bb = bh[ag];
#pragma unroll
    for (int m = 0; m < 2; ++m)
#pragma unroll
      for (int r = 0; r < 4; ++r) {
        float v = acc[m][n][r] + bb;
        pp[m][r] = fmaf(tanhf(v), q, pp[m][r]);
      }
  }
#pragma unroll
  for (int m = 0; m < 2; ++m)
#pragma unroll
    for (int r = 0; r < 4; ++r) {
#pragma unroll
      for (int o = 1; o < 16; o <<= 1)
        pp[m][r] += __shfl_xor(pp[m][r], o, 64);
    }
  __syncthreads();
  if (lc == 0) {
#pragma unroll
    for (int m = 0; m < 2; ++m)
#pragma unroll
      for (int r = 0; r < 4; ++r)
        red[w][m * 16 + lg * 4 + r] = pp[m][r];
  }
  __syncthreads();
  if (t < MT) {
    const int i = tile * MT + t;
    if (i < c0) {
      float sv = red[0][t] + red[1][t] + red[2][t] + red[3][t];
      int l = list[(size_t)b * L_ + i];
      probpart[((size_t)as * B_ + b) * L_ + l] = sv;
    }
  }
}

// ============ kernel 3: kT — softmax scalars + segment sums + 80 outputs ============
__global__ __launch_bounds__(256) void kT(const int* __restrict__ cnt,
                                          const int* __restrict__ list,
                                          const float* __restrict__ probpart,
                                          const float* __restrict__ ws_scal,
                                          const float* __restrict__ d,
                                          const int* __restrict__ starts,
                                          const int* __restrict__ endv,
                                          const float* __restrict__ bcls,
                                          float* __restrict__ out) {
  __shared__ float lg[L_];
  __shared__ float red[256];
  const int b = blockIdx.x;
  const int t = threadIdx.x;
  const float denom = ws_scal[0];
  const int c0 = cnt[b];

  // logits at masked positions; attended logits are exactly 0
  float mx = 0.0f;  // 0 participates (attended positions always exist)
  for (int i = t; i < c0; i += 256) {
    int l = list[(size_t)b * L_ + i];
    float s = probpart[((size_t)0 * B_ + b) * L_ + l]
            + probpart[((size_t)1 * B_ + b) * L_ + l]
            + probpart[((size_t)2 * B_ + b) * L_ + l]
            + probpart[((size_t)3 * B_ + b) * L_ + l];
    float v = -1000.0f * (s / denom);
    lg[i] = v;
    mx = fmaxf(mx, v);
  }
  red[t] = mx;
  __syncthreads();
  for (int off = 128; off >= 1; off >>= 1) {
    if (t < off) red[t] = fmaxf(red[t], red[t + off]);
    __syncthreads();
  }
  const float m = red[0];
  __syncthreads();

  float zs = 0.f;
  for (int i = t; i < c0; i += 256) zs += expf(lg[i] - m);
  if (t == 0) zs += (float)(L_ - c0) * expf(-m);
  red[t] = zs;
  __syncthreads();
  for (int off = 128; off >= 1; off >>= 1) {
    if (t < off) red[t] += red[t + off];
    __syncthreads();
  }
  const float Z = red[0];
  __syncthreads();
  const float att0 = expf(-m) / Z;   // att at every attended position

  for (int c = 0; c < C_; ++c) {
    const int st = starts[b * C_ + c];
    const int bound = (c < C_ - 1) ? (starts[b * C_ + c + 1] - 1) : (endv[b] - 1);
    const int lo = st + 1;
    const int hi = bound;
    float a = 0.f;
    for (int l = lo + t; l < hi; l += 256) a += d[(size_t)b * L_ + l];
    red[t] = a;
    __syncthreads();
    for (int off = 128; off >= 1; off >>= 1) {
      if (t < off) red[t] += red[t + off];
      __syncthreads();
    }
    if (t == 0) {
      int count = hi - lo;
      if (count < 0) count = 0;
      out[b * C_ + c] = red[0] + ws_scal[1] * att0 * (float)count + bcls[0];
    }
    __syncthreads();
  }
}

extern "C" void kernel_launch(void* const* d_in, const int* in_sizes, int n_in,
                              void* d_out, int out_size, void* d_ws, size_t ws_size,
                              hipStream_t stream) {
  const float* inp   = (const float*)d_in[0];
  const int*   attn  = (const int*)d_in[1];
  const int*   mlm   = (const int*)d_in[2];
  const float* Wh    = (const float*)d_in[3];
  const float* bh    = (const float*)d_in[4];
  const float* query = (const float*)d_in[5];
  const float* Wcls  = (const float*)d_in[6];
  const float* bcls  = (const float*)d_in[7];
  float* out = (float*)d_out;

  char* ws = (char*)d_ws;
  float*          ws_scal = (float*)(ws + OFF_SCAL);
  int*            endv    = (int*)(ws + OFF_END);
  int*            cnt     = (int*)(ws + OFF_CNT);
  int*            starts  = (int*)(ws + OFF_STARTS);
  int*            list    = (int*)(ws + OFF_LIST);
  unsigned short* W16     = (unsigned short*)(ws + OFF_W16);
  float*          probpart= (float*)(ws + OFF_PP);
  float*          dvec    = (float*)(ws + OFF_D);

  hipLaunchKernelGGL(kWA, dim3(B_ + 1 + KW_BLOCKS), dim3(256), 0, stream,
                     attn, mlm, query, Wcls, Wh, ws_scal, endv, cnt, starts, list, W16);
  hipLaunchKernelGGL(kMain, dim3(KC_BLOCKS + KE_BLOCKS), dim3(256), 0, stream,
                     inp, W16, bh, query, Wcls, attn, cnt, list, probpart, dvec);
  hipLaunchKernelGGL(kT, dim3(B_), dim3(256), 0, stream,
                     cnt, list, probpart, ws_scal, dvec, starts, endv, bcls, out);
}

// Round 7
// 64.334 us; speedup vs baseline: 1.5518x; 1.5518x over previous
//
#include <hip/hip_runtime.h>
#include <hip/hip_bf16.h>
#include <math.h>

#define B_ 16
#define L_ 2048
#define H_ 1024
#define A_ 1024
#define C_ 5

#define NSPLIT 4                 // A-dim split across blocks in MFMA part
#define MT 32                    // rows per tile
#define KPH 256                  // K per staging phase
#define TPB 16                   // tiles per batch (16*32=512 >= max masked 511)
#define KC_BLOCKS (B_ * TPB * NSPLIT)   // 1024 MFMA blocks
#define KE_BLOCKS (B_ * L_ / 16)        // 2048 streaming blocks (16 rows each)
#define KW_BLOCKS 64                    // Wfrag conversion blocks (one a_blk each)

typedef __attribute__((ext_vector_type(8))) short short8v;
typedef __attribute__((ext_vector_type(4))) float float4v;

// ---- workspace layout (bytes) ----
static constexpr size_t OFF_SCAL   = 0;        // 2 f: denom, wsum
static constexpr size_t OFF_END    = 64;       // B ints
static constexpr size_t OFF_CNT    = 192;      // B ints
static constexpr size_t OFF_STARTS = 320;      // B*C ints
static constexpr size_t OFF_LIST   = 4096;                              // B*L ints
static constexpr size_t OFF_WF     = OFF_LIST + (size_t)B_ * L_ * 4;    // A*H bf16 (fragment-swizzled)
static constexpr size_t OFF_PP     = OFF_WF + (size_t)A_ * H_ * 2;      // NSPLIT*B*L f
static constexpr size_t OFF_D      = OFF_PP + (size_t)NSPLIT * B_ * L_ * 4;  // B*L f

static __device__ __forceinline__ unsigned short f2bf(float f) {
  unsigned u = __float_as_uint(f);
  unsigned r = (u >> 16) & 1u;
  return (unsigned short)((u + 0x7fffu + r) >> 16);
}

// ============ kernel 1: kWA — masks + scalars + W -> fragment-swizzled bf16 ============
// blocks [0,B): per-batch mask compaction (wave-scan)
// block B: scalars (denom, wsum)
// blocks [B+1, B+1+64): Wfrag: frag (a_blk, k_blk) stored contiguous 1KB, lane-major:
//   Wfrag[((a_blk*32 + kb)*64 + l)*8 + j] = bf16(W[a_blk*16 + (l&15)][kb*32 + (l>>4)*8 + j])
__global__ __launch_bounds__(256) void kWA(const int* __restrict__ attn,
                                           const int* __restrict__ mlm,
                                           const float* __restrict__ query,
                                           const float* __restrict__ Wcls,
                                           const float* __restrict__ Wh,
                                           float* __restrict__ ws_scal,
                                           int* __restrict__ endv,
                                           int* __restrict__ cnt,
                                           int* __restrict__ starts,
                                           int* __restrict__ list,
                                           unsigned short* __restrict__ Wfrag) {
  __shared__ int   wsh[4];
  __shared__ float sf1[256];
  __shared__ float sf2[256];
  const int bid = blockIdx.x;
  const int t = threadIdx.x;

  if (bid < B_) {
    const int b = bid;
    const int* arow = attn + (size_t)b * L_;
    const int* mrow = mlm + (size_t)b * L_;
    const int w = t >> 6;
    const int lane = t & 63;
    const int base = t * 8;

    // ---- pass 1: attn==0 compaction (ascending) ----
    int loc[8];
    int lc = 0;
#pragma unroll
    for (int j = 0; j < 8; ++j) {
      int l = base + j;
      if (arow[l] == 0) loc[lc++] = l;
    }
    int incl = lc;
#pragma unroll
    for (int o = 1; o < 64; o <<= 1) {
      int v = __shfl_up(incl, o, 64);
      if (lane >= o) incl += v;
    }
    if (lane == 63) wsh[w] = incl;
    __syncthreads();
    int pre = 0, total = 0;
#pragma unroll
    for (int i = 0; i < 4; ++i) {
      int s = wsh[i];
      if (i < w) pre += s;
      total += s;
    }
    int excl = pre + incl - lc;
    int* lrow = list + (size_t)b * L_;
    for (int j = 0; j < lc; ++j) lrow[excl + j] = loc[j];
    if (t == 0) {
      cnt[b] = total;
      endv[b] = L_ - total;
    }
    __syncthreads();

    // ---- pass 2: mlm>0 markers ----
    int mloc[8];
    int mc = 0;
#pragma unroll
    for (int j = 0; j < 8; ++j) {
      int l = base + j;
      if (mrow[l] > 0) mloc[mc++] = l;
    }
    int incl2 = mc;
#pragma unroll
    for (int o = 1; o < 64; o <<= 1) {
      int v = __shfl_up(incl2, o, 64);
      if (lane >= o) incl2 += v;
    }
    if (lane == 63) wsh[w] = incl2;
    __syncthreads();
    int pre2 = 0;
#pragma unroll
    for (int i = 0; i < 4; ++i) {
      if (i < w) pre2 += wsh[i];
    }
    int excl2 = pre2 + incl2 - mc;
    for (int j = 0; j < mc; ++j) {
      int idx = excl2 + j;
      if (idx < C_) starts[b * C_ + idx] = mloc[j];
    }
  } else if (bid == B_) {
    // ---- scalars ----
    float s = 0.f, s2 = 0.f;
    for (int i = t; i < A_; i += 256) {
      float q = query[i];
      s += q;
      s2 = fmaf(q, q, s2);
    }
    sf1[t] = s;
    sf2[t] = s2;
    __syncthreads();
    for (int off = 128; off >= 1; off >>= 1) {
      if (t < off) {
        sf1[t] += sf1[t + off];
        sf2[t] += sf2[t + off];
      }
      __syncthreads();
    }
    float qsum = sf1[0], qsq = sf2[0];
    __syncthreads();
    float wv = 0.f;
    for (int i = t; i < H_; i += 256) wv += Wcls[i];
    sf1[t] = wv;
    __syncthreads();
    for (int off = 128; off >= 1; off >>= 1) {
      if (t < off) sf1[t] += sf1[t + off];
      __syncthreads();
    }
    if (t == 0) {
      float var = (qsq - qsum * qsum / (float)A_) / (float)(A_ - 1);
      ws_scal[0] = sqrtf((float)A_ * var);
      ws_scal[1] = sf1[0];
    }
  } else {
    // ---- Wfrag conversion: block handles one a_blk (16 a-rows) ----
    const int g = bid - B_ - 1;          // a_blk in [0,64)
    const int wv = t >> 6;
    const int l = t & 63;
    const int row = g * 16 + (l & 15);
    const int colb = (l >> 4) * 8;
    const float* srcrow = Wh + (size_t)row * H_;
#pragma unroll
    for (int i = 0; i < 8; ++i) {
      const int kb = wv * 8 + i;
      const float* src = srcrow + kb * 32 + colb;
      float4 u0 = *(const float4*)src;
      float4 u1 = *(const float4*)(src + 4);
      union { short8v v; unsigned short h[8]; } o;
      o.h[0] = f2bf(u0.x); o.h[1] = f2bf(u0.y); o.h[2] = f2bf(u0.z); o.h[3] = f2bf(u0.w);
      o.h[4] = f2bf(u1.x); o.h[5] = f2bf(u1.y); o.h[6] = f2bf(u1.z); o.h[7] = f2bf(u1.w);
      *(short8v*)(Wfrag + (((size_t)g * 32 + kb) * 64 + l) * 8) = o.v;
    }
  }
}

// ============ kernel 2: kMain — MFMA probs GEMM + full-row W_cls dots ============
// bids [0, KC_BLOCKS): MFMA; XCD-sibling layout: as=(bid>>3)&3, tb=(bid&7)|((bid>>5)<<3)
//   (4 as-siblings of a tile share bid%8 -> same XCD -> X L2 reuse)
//   B-operands load from Wfrag: contiguous 1KB per wave per fragment, no LDS, no barriers.
// bids [KC_BLOCKS, +KE_BLOCKS): streaming, 4 rows per wave, d[row]=dot(row,Wcls)
__global__ __launch_bounds__(256, 4) void kMain(const float* __restrict__ inp,
                                                const unsigned short* __restrict__ Wfrag,
                                                const float* __restrict__ bh,
                                                const float* __restrict__ query,
                                                const float* __restrict__ Wcls,
                                                const int* __restrict__ attn,
                                                const int* __restrict__ cnt,
                                                const int* __restrict__ list,
                                                float* __restrict__ probpart,
                                                float* __restrict__ d) {
  __shared__ __align__(16) unsigned short Xs[MT][KPH + 8];  // 32x264 bf16 = 16.9 KB
  __shared__ float red[4][MT];

  const int bid = blockIdx.x;
  const int t = threadIdx.x;
  const int w = t >> 6;
  const int lane = t & 63;

  if (bid >= KC_BLOCKS) {
    // ---- streaming part: 4 rows per wave ----
    const int r0 = (bid - KC_BLOCKS) * 16 + w * 4;
    const int a0v = attn[r0], a1v = attn[r0 + 1], a2v = attn[r0 + 2], a3v = attn[r0 + 3];
    if ((a0v | a1v | a2v | a3v) == 0) return;
    float4 wv4[4];
#pragma unroll
    for (int k = 0; k < 4; ++k) wv4[k] = *(const float4*)(Wcls + k * 256 + lane * 4);
    const float* p0 = inp + (size_t)r0 * H_;
    float4 x0[4], x1[4], x2[4], x3[4];
    if (a0v) {
#pragma unroll
      for (int k = 0; k < 4; ++k) x0[k] = *(const float4*)(p0 + k * 256 + lane * 4);
    }
    if (a1v) {
#pragma unroll
      for (int k = 0; k < 4; ++k) x1[k] = *(const float4*)(p0 + H_ + k * 256 + lane * 4);
    }
    if (a2v) {
#pragma unroll
      for (int k = 0; k < 4; ++k) x2[k] = *(const float4*)(p0 + 2 * H_ + k * 256 + lane * 4);
    }
    if (a3v) {
#pragma unroll
      for (int k = 0; k < 4; ++k) x3[k] = *(const float4*)(p0 + 3 * H_ + k * 256 + lane * 4);
    }
#define DOTROW(XV, AV, IDX)                                                          \
    if (AV) {                                                                        \
      float acc = 0.f;                                                               \
      _Pragma("unroll")                                                              \
      for (int k = 0; k < 4; ++k)                                                    \
        acc += XV[k].x * wv4[k].x + XV[k].y * wv4[k].y +                             \
               XV[k].z * wv4[k].z + XV[k].w * wv4[k].w;                              \
      _Pragma("unroll")                                                              \
      for (int o = 1; o < 64; o <<= 1) acc += __shfl_xor(acc, o, 64);                \
      if (lane == 0) d[r0 + IDX] = acc;                                              \
    }
    DOTROW(x0, a0v, 0)
    DOTROW(x1, a1v, 1)
    DOTROW(x2, a2v, 2)
    DOTROW(x3, a3v, 3)
#undef DOTROW
    return;
  }

  // ---- MFMA part ----
  const int as = (bid >> 3) & 3;
  const int tb = (bid & 7) | ((bid >> 5) << 3);   // [0, 256)
  const int b = tb >> 4;
  const int tile = tb & 15;
  const int c0 = cnt[b];
  if (tile * MT >= c0) return;

  const int lg = lane >> 4;
  const int lc = lane & 15;

  // staging decomposition: row = t>>3, col chunk = (t&7)*32 (32 f32 per thread/phase)
  const int srow = t >> 3;
  const int scol = (t & 7) * 32;
  const int gi = tile * MT + srow;
  const int gidx = (gi < c0) ? gi : (c0 - 1);     // clamp; duplicate rows harmless
  const int xl = list[(size_t)b * L_ + gidx];
  const float* xptr = inp + ((size_t)(b * L_ + xl)) * H_ + scol;

  // wave w covers a_blks (as*16 + w*4 + n), n=0..3; per-frag load = base + lane*16B
  const unsigned short* wfbase = Wfrag + ((size_t)(as * 16 + w * 4) * 32) * 512 + lane * 8;

  float4v acc[2][4];
#pragma unroll
  for (int m = 0; m < 2; ++m)
#pragma unroll
    for (int n = 0; n < 4; ++n) acc[m][n] = (float4v){0.f, 0.f, 0.f, 0.f};

  for (int ph = 0; ph < H_ / KPH; ++ph) {
    __syncthreads();   // previous phase's LDS reads done
    // stage X chunk: 32 rows x 256 cols (f32 -> bf16)
#pragma unroll
    for (int j = 0; j < 4; ++j) {
      float4 u0 = *(const float4*)(xptr + ph * KPH + j * 8);
      float4 u1 = *(const float4*)(xptr + ph * KPH + j * 8 + 4);
      union { short8v v; unsigned short h[8]; } o;
      o.h[0] = f2bf(u0.x); o.h[1] = f2bf(u0.y); o.h[2] = f2bf(u0.z); o.h[3] = f2bf(u0.w);
      o.h[4] = f2bf(u1.x); o.h[5] = f2bf(u1.y); o.h[6] = f2bf(u1.z); o.h[7] = f2bf(u1.w);
      *(short8v*)&Xs[srow][scol + j * 8] = o.v;
    }
    __syncthreads();   // tile ready
    // 8 barrier-free K=32 sub-steps; coalesced B frags stream from L2 under MFMA
#pragma unroll
    for (int kk = 0; kk < 8; ++kk) {
      const int kb = ph * 8 + kk;
      const unsigned short* fp = wfbase + (size_t)kb * 512;
      short8v bv0 = *(const short8v*)(fp);
      short8v bv1 = *(const short8v*)(fp + 32 * 512);
      short8v bv2 = *(const short8v*)(fp + 64 * 512);
      short8v bv3 = *(const short8v*)(fp + 96 * 512);
      const int off = kk * 32 + lg * 8;
      short8v av0 = *(const short8v*)&Xs[lc][off];
      short8v av1 = *(const short8v*)&Xs[16 + lc][off];
      acc[0][0] = __builtin_amdgcn_mfma_f32_16x16x32_bf16(av0, bv0, acc[0][0], 0, 0, 0);
      acc[1][0] = __builtin_amdgcn_mfma_f32_16x16x32_bf16(av1, bv0, acc[1][0], 0, 0, 0);
      acc[0][1] = __builtin_amdgcn_mfma_f32_16x16x32_bf16(av0, bv1, acc[0][1], 0, 0, 0);
      acc[1][1] = __builtin_amdgcn_mfma_f32_16x16x32_bf16(av1, bv1, acc[1][1], 0, 0, 0);
      acc[0][2] = __builtin_amdgcn_mfma_f32_16x16x32_bf16(av0, bv2, acc[0][2], 0, 0, 0);
      acc[1][2] = __builtin_amdgcn_mfma_f32_16x16x32_bf16(av1, bv2, acc[1][2], 0, 0, 0);
      acc[0][3] = __builtin_amdgcn_mfma_f32_16x16x32_bf16(av0, bv3, acc[0][3], 0, 0, 0);
      acc[1][3] = __builtin_amdgcn_mfma_f32_16x16x32_bf16(av1, bv3, acc[1][3], 0, 0, 0);
    }
  }

  // epilogue: bias + tanh + *query, reduce over this wave's 64 a-cols
  float pp[2][4];
#pragma unroll
  for (int m = 0; m < 2; ++m)
#pragma unroll
    for (int r = 0; r < 4; ++r) pp[m][r] = 0.f;

#pragma unroll
  for (int n = 0; n < 4; ++n) {
    const int ag = as * 256 + w * 64 + n * 16 + lc;
    const float q = query[ag];
    const float bb = bh[ag];
#pragma unroll
    for (int m = 0; m < 2; ++m)
#pragma unroll
      for (int r = 0; r < 4; ++r) {
        float v = acc[m][n][r] + bb;
        pp[m][r] = fmaf(tanhf(v), q, pp[m][r]);
      }
  }
#pragma unroll
  for (int m = 0; m < 2; ++m)
#pragma unroll
    for (int r = 0; r < 4; ++r) {
#pragma unroll
      for (int o = 1; o < 16; o <<= 1)
        pp[m][r] += __shfl_xor(pp[m][r], o, 64);
    }
  __syncthreads();
  if (lc == 0) {
#pragma unroll
    for (int m = 0; m < 2; ++m)
#pragma unroll
      for (int r = 0; r < 4; ++r)
        red[w][m * 16 + lg * 4 + r] = pp[m][r];
  }
  __syncthreads();
  if (t < MT) {
    const int i = tile * MT + t;
    if (i < c0) {
      float sv = red[0][t] + red[1][t] + red[2][t] + red[3][t];
      int l = list[(size_t)b * L_ + i];
      probpart[((size_t)as * B_ + b) * L_ + l] = sv;
    }
  }
}

// ============ kernel 3: kT — softmax scalars + segment sums + 80 outputs ============
__global__ __launch_bounds__(256) void kT(const int* __restrict__ cnt,
                                          const int* __restrict__ list,
                                          const float* __restrict__ probpart,
                                          const float* __restrict__ ws_scal,
                                          const float* __restrict__ d,
                                          const int* __restrict__ starts,
                                          const int* __restrict__ endv,
                                          const float* __restrict__ bcls,
                                          float* __restrict__ out) {
  __shared__ float lg[L_];
  __shared__ float red[256];
  const int b = blockIdx.x;
  const int t = threadIdx.x;
  const float denom = ws_scal[0];
  const int c0 = cnt[b];

  // logits at masked positions; attended logits are exactly 0
  float mx = 0.0f;  // 0 participates (attended positions always exist)
  for (int i = t; i < c0; i += 256) {
    int l = list[(size_t)b * L_ + i];
    float s = probpart[((size_t)0 * B_ + b) * L_ + l]
            + probpart[((size_t)1 * B_ + b) * L_ + l]
            + probpart[((size_t)2 * B_ + b) * L_ + l]
            + probpart[((size_t)3 * B_ + b) * L_ + l];
    float v = -1000.0f * (s / denom);
    lg[i] = v;
    mx = fmaxf(mx, v);
  }
  red[t] = mx;
  __syncthreads();
  for (int off = 128; off >= 1; off >>= 1) {
    if (t < off) red[t] = fmaxf(red[t], red[t + off]);
    __syncthreads();
  }
  const float m = red[0];
  __syncthreads();

  float zs = 0.f;
  for (int i = t; i < c0; i += 256) zs += expf(lg[i] - m);
  if (t == 0) zs += (float)(L_ - c0) * expf(-m);
  red[t] = zs;
  __syncthreads();
  for (int off = 128; off >= 1; off >>= 1) {
    if (t < off) red[t] += red[t + off];
    __syncthreads();
  }
  const float Z = red[0];
  __syncthreads();
  const float att0 = expf(-m) / Z;   // att at every attended position

  for (int c = 0; c < C_; ++c) {
    const int st = starts[b * C_ + c];
    const int bound = (c < C_ - 1) ? (starts[b * C_ + c + 1] - 1) : (endv[b] - 1);
    const int lo = st + 1;
    const int hi = bound;
    float a = 0.f;
    for (int l = lo + t; l < hi; l += 256) a += d[(size_t)b * L_ + l];
    red[t] = a;
    __syncthreads();
    for (int off = 128; off >= 1; off >>= 1) {
      if (t < off) red[t] += red[t + off];
      __syncthreads();
    }
    if (t == 0) {
      int count = hi - lo;
      if (count < 0) count = 0;
      out[b * C_ + c] = red[0] + ws_scal[1] * att0 * (float)count + bcls[0];
    }
    __syncthreads();
  }
}

extern "C" void kernel_launch(void* const* d_in, const int* in_sizes, int n_in,
                              void* d_out, int out_size, void* d_ws, size_t ws_size,
                              hipStream_t stream) {
  const float* inp   = (const float*)d_in[0];
  const int*   attn  = (const int*)d_in[1];
  const int*   mlm   = (const int*)d_in[2];
  const float* Wh    = (const float*)d_in[3];
  const float* bh    = (const float*)d_in[4];
  const float* query = (const float*)d_in[5];
  const float* Wcls  = (const float*)d_in[6];
  const float* bcls  = (const float*)d_in[7];
  float* out = (float*)d_out;

  char* ws = (char*)d_ws;
  float*          ws_scal = (float*)(ws + OFF_SCAL);
  int*            endv    = (int*)(ws + OFF_END);
  int*            cnt     = (int*)(ws + OFF_CNT);
  int*            starts  = (int*)(ws + OFF_STARTS);
  int*            list    = (int*)(ws + OFF_LIST);
  unsigned short* Wfrag   = (unsigned short*)(ws + OFF_WF);
  float*          probpart= (float*)(ws + OFF_PP);
  float*          dvec    = (float*)(ws + OFF_D);

  hipLaunchKernelGGL(kWA, dim3(B_ + 1 + KW_BLOCKS), dim3(256), 0, stream,
                     attn, mlm, query, Wcls, Wh, ws_scal, endv, cnt, starts, list, Wfrag);
  hipLaunchKernelGGL(kMain, dim3(KC_BLOCKS + KE_BLOCKS), dim3(256), 0, stream,
                     inp, Wfrag, bh, query, Wcls, attn, cnt, list, probpart, dvec);
  hipLaunchKernelGGL(kT, dim3(B_), dim3(256), 0, stream,
                     cnt, list, probpart, ws_scal, dvec, starts, endv, bcls, out);
}